// Round 4
// baseline (11921.525 us; speedup 1.0000x reference)
//
#include <hip/hip_runtime.h>
#include <cstdint>
#include <cstddef>

// Rank1BayesianRNN on MI355X — round 4: persistent kernel.
// 256 WGs x 256 threads (1 WG/CU, forced by 128 KiB LDS). Each WG holds its
// 64-col x 1024-K folded bf16 weight slice (hi plane) LDS-resident for the
// whole recurrence; A-side (x, h) kept fp32-accurate via bf16 hi/lo 2-term
// MFMA; c,h state in registers; one spin grid-barrier per phase (257 phases:
// layer0 step t || layer1 step t-1). Head = 2 small global-B GEMMs.

typedef __attribute__((ext_vector_type(8))) short  s16x8;
typedef __attribute__((ext_vector_type(8))) __bf16 bf16x8;
typedef __attribute__((ext_vector_type(4))) float  f32x4;

#define NWG 256

__device__ __forceinline__ short f2bfs(float f) {
  union { float f; unsigned u; } v; v.f = f;
  unsigned r = v.u + 0x7FFFu + ((v.u >> 16) & 1u);   // RNE
  return (short)(r >> 16);
}
__device__ __forceinline__ float bf2f(short s) {
  union { unsigned u; float f; } v; v.u = ((unsigned)(unsigned short)s) << 16;
  return v.f;
}
__device__ __forceinline__ void split2(float v, short& hi, short& lo) {
  hi = f2bfs(v);
  lo = f2bfs(v - bf2f(hi));
}
__device__ __forceinline__ float sigf(float x) { return 1.0f / (1.0f + __expf(-x)); }

// Sense-reversal grid barrier. Release/acquire at agent scope handles
// cross-XCD L2 (wbl2/inv emitted by the atomics); __syncthreads before
// arrival drains each wave's stores to L2 first.
__device__ __forceinline__ void gridbar(unsigned* cnt, unsigned* gen) {
  __syncthreads();
  if (threadIdx.x == 0) {
    unsigned g = __hip_atomic_load(gen, __ATOMIC_RELAXED, __HIP_MEMORY_SCOPE_AGENT);
    unsigned a = __hip_atomic_fetch_add(cnt, 1u, __ATOMIC_ACQ_REL,
                                        __HIP_MEMORY_SCOPE_AGENT);
    if (a == NWG - 1) {
      __hip_atomic_store(cnt, 0u, __ATOMIC_RELAXED, __HIP_MEMORY_SCOPE_AGENT);
      __hip_atomic_store(gen, g + 1u, __ATOMIC_RELEASE, __HIP_MEMORY_SCOPE_AGENT);
    } else {
      long spins = 0;
      while (__hip_atomic_load(gen, __ATOMIC_ACQUIRE,
                               __HIP_MEMORY_SCOPE_AGENT) == g) {
        __builtin_amdgcn_s_sleep(2);
        if (++spins > (1L << 23)) break;   // safety: terminate, don't hang
      }
    }
  }
  __syncthreads();
}

// ---------------------------------------------------------------------------
// Persistent LSTM: wg = [layer(1) | rb(2) | cb(5)]; tile = rows rb*64..+64,
// cols cb*64..+64 (gate-interleaved: col = gate*16 + unit_lo, unit block cb).
// ---------------------------------------------------------------------------
__global__ __launch_bounds__(256, 1) void lstm_persist(
    const float* __restrict__ seq,
    short* __restrict__ h0hi, short* __restrict__ h0lo,
    short* __restrict__ h1hi, short* __restrict__ h1lo,
    const short* __restrict__ Wf, const float* __restrict__ biasF,
    const int* __restrict__ slen, unsigned* __restrict__ bar)
{
  extern __shared__ short Bs[];                 // [64 cols][1024 k] = 128 KiB
  const int wg = blockIdx.x;
  const int layer = wg >> 7;
  const int idx = wg & 127;
  const int cb = idx & 31, rb = idx >> 5;       // ensemble e == rb
  const int tid = threadIdx.x, wave = tid >> 6, lane = tid & 63;

  // ---- stage weight slice into LDS (hi plane), XOR-swizzled ----
  const short* Wfe = Wf + ((size_t)(layer * 4 + rb) * 2048 + cb * 64) * 1024;
  #pragma unroll
  for (int i = 0; i < 32; ++i) {
    int f = tid + (i << 8);
    int r = f >> 7, kc = (f & 127) << 3;        // r = col 0..63
    s16x8 v = *reinterpret_cast<const s16x8*>(Wfe + (size_t)r * 1024 + kc);
    int byo = ((r << 11) + (kc << 1)) ^ ((r & 7) << 4);
    *reinterpret_cast<s16x8*>(reinterpret_cast<char*>(Bs) + byo) = v;
  }
  __syncthreads();

  const int j = lane & 15;
  const int rbase = rb * 64 + wave * 16 + ((lane >> 4) << 2);
  const int rowg  = rb * 64 + wave * 16 + j;
  const int koff  = (lane >> 4) << 3;
  const int u     = cb * 16 + j;
  const float* bp = biasF + (size_t)(layer * 4 + rb) * 2048 + cb * 64 + j;
  const float bi = bp[0], bff = bp[16], bg = bp[32], bo = bp[48];
  int msl[4];
  #pragma unroll
  for (int r = 0; r < 4; ++r) msl[r] = slen[rbase + r];

  float creg[4] = {0.f, 0.f, 0.f, 0.f};
  float hreg[4] = {0.f, 0.f, 0.f, 0.f};
  const size_t BH = (size_t)256 * 512;
  unsigned* cnt = bar; unsigned* gen = bar + 1;
  const char* bs = reinterpret_cast<const char*>(Bs);

  for (int t = 0; t <= 256; ++t) {
    const int s = t - layer;
    if (s >= 0 && s < 256) {
      const int cur = s & 1;
      const short* hPhi = (layer ? h1hi : h0hi) + (size_t)cur * BH;
      const short* hPlo = (layer ? h1lo : h0lo) + (size_t)cur * BH;
      short* hOhi = (layer ? h1hi : h0hi) + (size_t)(cur ^ 1) * BH;
      short* hOlo = (layer ? h1lo : h0lo) + (size_t)(cur ^ 1) * BH;

      f32x4 acc[4] = {}, accL[4] = {};

      #define MMQ(KLOC, AHI, ALO)                                              \
        {                                                                      \
          _Pragma("unroll")                                                    \
          for (int cf = 0; cf < 4; ++cf) {                                     \
            const int ccol = (cf << 4) + j;                                    \
            const int byo =                                                    \
                (((ccol << 10) + (KLOC)) << 1) ^ ((ccol & 7) << 4);            \
            s16x8 b = *reinterpret_cast<const s16x8*>(bs + byo);               \
            acc[cf] = __builtin_amdgcn_mfma_f32_16x16x32_bf16(                 \
                __builtin_bit_cast(bf16x8, AHI), __builtin_bit_cast(bf16x8, b),\
                acc[cf], 0, 0, 0);                                             \
            accL[cf] = __builtin_amdgcn_mfma_f32_16x16x32_bf16(                \
                __builtin_bit_cast(bf16x8, ALO), __builtin_bit_cast(bf16x8, b),\
                accL[cf], 0, 0, 0);                                            \
          }                                                                    \
        }

      // half 0 (k 0..511): layer0 <- x (fp32, split on the fly);
      //                    layer1 <- h0 of this step (hi/lo).
      if (layer == 0) {
        const float* xr = seq + (size_t)rowg * 131072 + (size_t)s * 512 + koff;
        #pragma unroll 4
        for (int ks = 0; ks < 16; ++ks) {
          const int kloc = (ks << 5) + koff;
          const float* p = xr + (ks << 5);
          float4 x0 = *reinterpret_cast<const float4*>(p);
          float4 x1 = *reinterpret_cast<const float4*>(p + 4);
          float xv[8] = {x0.x, x0.y, x0.z, x0.w, x1.x, x1.y, x1.z, x1.w};
          s16x8 ahi, alo;
          #pragma unroll
          for (int q = 0; q < 8; ++q) {
            union { float f; unsigned u; } vv; vv.f = xv[q];
            short h = (short)(vv.u >> 16);            // truncate -> hi
            ahi[q] = h;
            alo[q] = f2bfs(xv[q] - bf2f(h));          // residual -> lo
          }
          MMQ(kloc, ahi, alo)
        }
      } else {
        const short* xh = h0hi + (size_t)(cur ^ 1) * BH + (size_t)rowg * 512 + koff;
        const short* xl = h0lo + (size_t)(cur ^ 1) * BH + (size_t)rowg * 512 + koff;
        #pragma unroll 4
        for (int ks = 0; ks < 16; ++ks) {
          const int kloc = (ks << 5) + koff;
          s16x8 ahi = *reinterpret_cast<const s16x8*>(xh + (ks << 5));
          s16x8 alo = *reinterpret_cast<const s16x8*>(xl + (ks << 5));
          MMQ(kloc, ahi, alo)
        }
      }
      // half 1 (k 512..1023): own previous h (hi/lo)
      {
        const short* ph = hPhi + (size_t)rowg * 512 + koff;
        const short* pl = hPlo + (size_t)rowg * 512 + koff;
        #pragma unroll 4
        for (int ks = 0; ks < 16; ++ks) {
          const int kloc = 512 + (ks << 5) + koff;
          s16x8 ahi = *reinterpret_cast<const s16x8*>(ph + (ks << 5));
          s16x8 alo = *reinterpret_cast<const s16x8*>(pl + (ks << 5));
          MMQ(kloc, ahi, alo)
        }
      }
      #undef MMQ

      // ---- LSTM cell, state in registers ----
      #pragma unroll
      for (int r = 0; r < 4; ++r) {
        const int row = rbase + r;
        float zi = acc[0][r] + accL[0][r] + bi;
        float zf = acc[1][r] + accL[1][r] + bff;
        float zg = acc[2][r] + accL[2][r] + bg;
        float zo = acc[3][r] + accL[3][r] + bo;
        float cn = sigf(zf) * creg[r] + sigf(zi) * tanhf(zg);
        float hn = sigf(zo) * tanhf(cn);
        if (s >= msl[r]) { cn = creg[r]; hn = hreg[r]; }   // masked: carry
        creg[r] = cn; hreg[r] = hn;
        short hh, hl; split2(hn, hh, hl);
        hOhi[(size_t)row * 512 + u] = hh;
        hOlo[(size_t)row * 512 + u] = hl;
      }
    }
    if (t < 256) gridbar(cnt, gen);
  }
}

// ---------------------------------------------------------------------------
// Head GEMM: 64x64 tile, B hi from global, A hi/lo, 2-term MFMA.
// EPI 1 = relu6 -> hi/lo bf16; EPI 2 = f32 out.
// ---------------------------------------------------------------------------
template<int EPI>
__global__ __launch_bounds__(256) void head_gemm(
    const short* __restrict__ a0hi, const short* __restrict__ a0lo, int sA0,
    const short* __restrict__ a1hi, const short* __restrict__ a1lo, int sA1,
    int kSplit, const short* __restrict__ Wh, const float* __restrict__ bias,
    int N, int K,
    short* __restrict__ outhi, short* __restrict__ outlo,
    float* __restrict__ outf)
{
  const int cb = blockIdx.x, rb = blockIdx.y;   // e == rb
  const int tid = threadIdx.x, wave = tid >> 6, lane = tid & 63;
  const int j = lane & 15;
  const int rowg = rb * 64 + wave * 16 + j;
  const int koff = (lane >> 4) << 3;
  const short* We = Wh + ((size_t)rb * N + cb * 64) * K;
  f32x4 acc[4] = {}, accL[4] = {};
  for (int ks = 0; ks < (K >> 5); ++ks) {
    const int kloc = (ks << 5) + koff;
    s16x8 ahi, alo;
    if (kloc < kSplit) {
      ahi = *reinterpret_cast<const s16x8*>(a0hi + (size_t)rowg * sA0 + kloc);
      alo = *reinterpret_cast<const s16x8*>(a0lo + (size_t)rowg * sA0 + kloc);
    } else {
      ahi = *reinterpret_cast<const s16x8*>(a1hi + (size_t)rowg * sA1 + kloc - kSplit);
      alo = *reinterpret_cast<const s16x8*>(a1lo + (size_t)rowg * sA1 + kloc - kSplit);
    }
    #pragma unroll
    for (int cf = 0; cf < 4; ++cf) {
      const int ccol = (cf << 4) + j;
      s16x8 b = *reinterpret_cast<const s16x8*>(We + (size_t)ccol * K + kloc);
      acc[cf] = __builtin_amdgcn_mfma_f32_16x16x32_bf16(
          __builtin_bit_cast(bf16x8, ahi), __builtin_bit_cast(bf16x8, b),
          acc[cf], 0, 0, 0);
      accL[cf] = __builtin_amdgcn_mfma_f32_16x16x32_bf16(
          __builtin_bit_cast(bf16x8, alo), __builtin_bit_cast(bf16x8, b),
          accL[cf], 0, 0, 0);
    }
  }
  const int rbase = rb * 64 + wave * 16 + ((lane >> 4) << 2);
  #pragma unroll
  for (int cf = 0; cf < 4; ++cf) {
    const int col = cb * 64 + cf * 16 + j;
    const float bb = bias[(size_t)rb * N + col];
    #pragma unroll
    for (int r = 0; r < 4; ++r) {
      float z = acc[cf][r] + accL[cf][r] + bb;
      if (EPI == 1) {
        z = fminf(fmaxf(z, 0.f), 6.f);
        short hh, hl; split2(z, hh, hl);
        outhi[(size_t)(rbase + r) * N + col] = hh;
        outlo[(size_t)(rbase + r) * N + col] = hl;
      } else {
        outf[(size_t)(rbase + r) * N + col] = z;
      }
    }
  }
}

// ---------------------------------------------------------------------------
// Prep: fold alpha/gamma into per-ensemble bf16 (hi-only) weights.
// LSTM layout: Wf[le][c'][k], c' = ublk*64 + gate*16 + unit_lo, k = W|U.
// ---------------------------------------------------------------------------
__global__ __launch_bounds__(256) void fold_lstm(
    const float* __restrict__ W, const float* __restrict__ U,
    const float* __restrict__ al, const float* __restrict__ ral,
    const float* __restrict__ ga, const float* __restrict__ rga,
    short* __restrict__ Wf)
{
  __shared__ float T[64][65];
  const int tid = threadIdx.x;
  const int kb = blockIdx.x * 64;   // over K=1024 (W 512 | U 512)
  const int cb = blockIdx.y;        // ublk 0..31
  const int le = blockIdx.z;        // l*4+e
  const int l  = le >> 2;
  const int kl = tid >> 2;
  const int g  = tid & 3;
  const int k  = kb + kl;
  const bool isW = k < 512;
  const int kk = isW ? k : k - 512;
  const float* src = (isW ? W : U) + ((size_t)l * 512 + kk) * 2048;
  const float  a   = (isW ? al : ral)[(size_t)le * 512 + kk];
  const float* gam = (isW ? ga : rga) + (size_t)le * 2048;
  const int colBase = g * 512 + cb * 16;
  const float4* s4 = reinterpret_cast<const float4*>(src + colBase);
  const float4* g4 = reinterpret_cast<const float4*>(gam + colBase);
  #pragma unroll
  for (int q = 0; q < 4; ++q) {
    float4 v = s4[q], gv = g4[q];
    T[kl][g * 16 + q * 4 + 0] = v.x * a * gv.x;
    T[kl][g * 16 + q * 4 + 1] = v.y * a * gv.y;
    T[kl][g * 16 + q * 4 + 2] = v.z * a * gv.z;
    T[kl][g * 16 + q * 4 + 3] = v.w * a * gv.w;
  }
  __syncthreads();
  const int cl = tid >> 2, kq0 = (tid & 3) * 16;
  alignas(16) short tH[16];
  #pragma unroll
  for (int q = 0; q < 16; ++q) tH[q] = f2bfs(T[kq0 + q][cl]);
  size_t dst = ((size_t)le * 2048 + cb * 64 + cl) * 1024 + kb + kq0;
  *reinterpret_cast<s16x8*>(Wf + dst)     = *reinterpret_cast<s16x8*>(tH);
  *reinterpret_cast<s16x8*>(Wf + dst + 8) = *reinterpret_cast<s16x8*>(tH + 8);
}

// Head: dst[e][col][k] = src[k][col]*alpha[e][k]*gamma[e][col]  (hi only)
__global__ __launch_bounds__(256) void fold_plain(
    const float* __restrict__ src, const float* __restrict__ al,
    const float* __restrict__ ga, short* __restrict__ dst, int N, int K)
{
  __shared__ float T[64][65];
  const int tid = threadIdx.x;
  const int kb = blockIdx.x * 64;
  const int nb = blockIdx.y;
  const int e  = blockIdx.z;
  const int kl = tid >> 2;
  const int c0 = (tid & 3) * 16;
  const int k  = kb + kl;
  const float a = al[(size_t)e * K + k];
  const int colBase = nb * 64 + c0;
  const float4* s4 = reinterpret_cast<const float4*>(src + (size_t)k * N + colBase);
  const float4* g4 = reinterpret_cast<const float4*>(ga + (size_t)e * N + colBase);
  #pragma unroll
  for (int q = 0; q < 4; ++q) {
    float4 v = s4[q], gv = g4[q];
    T[kl][c0 + q * 4 + 0] = v.x * a * gv.x;
    T[kl][c0 + q * 4 + 1] = v.y * a * gv.y;
    T[kl][c0 + q * 4 + 2] = v.z * a * gv.z;
    T[kl][c0 + q * 4 + 3] = v.w * a * gv.w;
  }
  __syncthreads();
  const int cl = tid >> 2, kq0 = (tid & 3) * 16;
  alignas(16) short tH[16];
  #pragma unroll
  for (int q = 0; q < 16; ++q) tH[q] = f2bfs(T[kq0 + q][cl]);
  size_t d = ((size_t)e * N + nb * 64 + cl) * K + kb + kq0;
  *reinterpret_cast<s16x8*>(dst + d)     = *reinterpret_cast<s16x8*>(tH);
  *reinterpret_cast<s16x8*>(dst + d + 8) = *reinterpret_cast<s16x8*>(tH + 8);
}

__global__ void fold_bias_lstm(const float* __restrict__ b, float* __restrict__ bf) {
  int idx = blockIdx.x * 256 + threadIdx.x;          // 16384
  int cp = idx & 2047, le = idx >> 11;
  int ublk = cp >> 6, g = (cp >> 4) & 3, jj = cp & 15;
  bf[idx] = b[(size_t)le * 2048 + g * 512 + ublk * 16 + jj];
}

__global__ void cvt_split(const float* __restrict__ s,
                          short* __restrict__ hi, short* __restrict__ lo, int n) {
  int i = blockIdx.x * blockDim.x + threadIdx.x;
  if (i < n) { short h, l; split2(s[i], h, l); hi[i] = h; lo[i] = l; }
}

__global__ void zero_ws(float4* p, int n) {
  int i = blockIdx.x * blockDim.x + threadIdx.x;
  if (i < n) p[i] = make_float4(0.f, 0.f, 0.f, 0.f);
}

__global__ void init_bar(unsigned* bar) {
  if (threadIdx.x < 4) bar[threadIdx.x] = 0u;
}

// ---------------------------------------------------------------------------
// workspace layout (bytes)
// ---------------------------------------------------------------------------
constexpr size_t OFF_WF    = 0;                        // 2*4*2048*1024*2 = 33554432
constexpr size_t OFF_WHID  = 33554432;                 // 4*256*768*2     = 1572864
constexpr size_t OFF_WOUT  = OFF_WHID + 1572864;       // 4*64*256*2      = 131072
constexpr size_t OFF_BIASF = OFF_WOUT + 131072;        // 16384*4         = 65536
constexpr size_t OFF_CTXH  = OFF_BIASF + 65536;        // 65536*2         = 131072
constexpr size_t OFF_CTXL  = OFF_CTXH + 131072;
constexpr size_t OFF_H0HI  = OFF_CTXL + 131072;        // 2*256*512*2     = 524288
constexpr size_t OFF_H0LO  = OFF_H0HI + 524288;
constexpr size_t OFF_H1HI  = OFF_H0LO + 524288;
constexpr size_t OFF_H1LO  = OFF_H1HI + 524288;
constexpr size_t OFF_HIDH  = OFF_H1LO + 524288;        // 256*256*2       = 131072
constexpr size_t OFF_HIDL  = OFF_HIDH + 131072;
constexpr size_t OFF_BAR   = OFF_HIDL + 131072;        // 16

extern "C" void kernel_launch(void* const* d_in, const int* in_sizes, int n_in,
                              void* d_out, int out_size, void* d_ws, size_t ws_size,
                              hipStream_t stream) {
  (void)in_sizes; (void)n_in; (void)out_size; (void)ws_size;
  const float* seq  = (const float*)d_in[0];
  const float* ctx  = (const float*)d_in[1];
  const int*   slen = (const int*)d_in[2];
  const float* lW   = (const float*)d_in[3];
  const float* lU   = (const float*)d_in[4];
  const float* lb   = (const float*)d_in[5];
  const float* lal  = (const float*)d_in[6];
  const float* lga  = (const float*)d_in[7];
  const float* lral = (const float*)d_in[8];
  const float* lrga = (const float*)d_in[9];
  const float* hW   = (const float*)d_in[10];
  const float* hb   = (const float*)d_in[11];
  const float* hal  = (const float*)d_in[12];
  const float* hga  = (const float*)d_in[13];
  const float* oW   = (const float*)d_in[14];
  const float* ob   = (const float*)d_in[15];
  const float* oal  = (const float*)d_in[16];
  const float* oga  = (const float*)d_in[17];

  char* ws = (char*)d_ws;
  short* Wf    = (short*)(ws + OFF_WF);
  short* Whid  = (short*)(ws + OFF_WHID);
  short* Wout  = (short*)(ws + OFF_WOUT);
  float* biasF = (float*)(ws + OFF_BIASF);
  short* ctxhi = (short*)(ws + OFF_CTXH);
  short* ctxlo = (short*)(ws + OFF_CTXL);
  short* h0hi  = (short*)(ws + OFF_H0HI);
  short* h0lo  = (short*)(ws + OFF_H0LO);
  short* h1hi  = (short*)(ws + OFF_H1HI);
  short* h1lo  = (short*)(ws + OFF_H1LO);
  short* hidhi = (short*)(ws + OFF_HIDH);
  short* hidlo = (short*)(ws + OFF_HIDL);
  unsigned* bar = (unsigned*)(ws + OFF_BAR);

  // allow 128 KiB dynamic LDS (ignore error; no-op where unnecessary)
  (void)hipFuncSetAttribute(reinterpret_cast<const void*>(lstm_persist),
                            hipFuncAttributeMaxDynamicSharedMemorySize, 131072);

  // prep (every call: deterministic, no caching)
  fold_lstm<<<dim3(16, 32, 8), 256, 0, stream>>>(lW, lU, lal, lral, lga, lrga, Wf);
  fold_plain<<<dim3(12, 4, 4), 256, 0, stream>>>(hW, hal, hga, Whid, 256, 768);
  fold_plain<<<dim3(4, 1, 4), 256, 0, stream>>>(oW, oal, oga, Wout, 64, 256);
  fold_bias_lstm<<<64, 256, 0, stream>>>(lb, biasF);
  cvt_split<<<256, 256, 0, stream>>>(ctx, ctxhi, ctxlo, 65536);
  zero_ws<<<512, 256, 0, stream>>>((float4*)(ws + OFF_H0HI), 2097152 / 16);
  init_bar<<<1, 64, 0, stream>>>(bar);

  // the whole recurrence in one persistent kernel
  lstm_persist<<<NWG, 256, 131072, stream>>>(seq, h0hi, h0lo, h1hi, h1lo,
                                             Wf, biasF, slen, bar);

  // head: hidden = relu6(((h1,ctx)*a)@hid_W*g + b); out = ((hid*a)@out_W*g + b)
  head_gemm<1><<<dim3(4, 4), 256, 0, stream>>>(
      h1hi /* final h1 in buf0 */, h1lo, 512,
      ctxhi, ctxlo, 256, 512,
      Whid, hb, 256, 768, hidhi, hidlo, nullptr);
  head_gemm<2><<<dim3(1, 4), 256, 0, stream>>>(
      hidhi, hidlo, 256,
      hidhi, hidlo, 256, 256,
      Wout, ob, 64, 256,
      nullptr, nullptr, (float*)d_out);
}

// Round 5
// 4540.599 us; speedup vs baseline: 2.6255x; 2.6255x over previous
//
#include <hip/hip_runtime.h>
#include <cstdint>
#include <cstddef>

// Rank1BayesianRNN on MI355X — round 5: persistent kernel, fixed sync + LDS.
// vs round 4 (49us/step, MfmaUtil 3.5%, 1.3e8 LDS conflicts):
//  * monotonic per-rb barriers: RELAXED arrive/spin (plain sc1 traffic, no
//    per-poll buffer_inv), ONE acquire fence per step per WG.
//  * h state packed (hi|lo uint32), written via sc1 dword stores
//    (__hip_atomic_store RELAXED/AGENT) -> no buffer_wbl2 needed anywhere;
//    consumers read cached (post-inv) for cross-WG L2 reuse.
//  * conflict-free fragment-linear LDS layout (staging fully coalesced).
// Numerics identical to round 3/4 (absmax 0.0078): weights bf16-hi folded,
// A-side fp32 via bf16 hi/lo 2-term MFMA, c/h fp32 in registers.

typedef __attribute__((ext_vector_type(8))) short  s16x8;
typedef __attribute__((ext_vector_type(8))) __bf16 bf16x8;
typedef __attribute__((ext_vector_type(4))) float  f32x4;

__device__ __forceinline__ short f2bfs(float f) {
  union { float f; unsigned u; } v; v.f = f;
  unsigned r = v.u + 0x7FFFu + ((v.u >> 16) & 1u);   // RNE
  return (short)(r >> 16);
}
__device__ __forceinline__ float bf2f(short s) {
  union { unsigned u; float f; } v; v.u = ((unsigned)(unsigned short)s) << 16;
  return v.f;
}
__device__ __forceinline__ void split2(float v, short& hi, short& lo) {
  hi = f2bfs(v);
  lo = f2bfs(v - bf2f(hi));
}
__device__ __forceinline__ float sigf(float x) { return 1.0f / (1.0f + __expf(-x)); }

__device__ __forceinline__ void unpack8(const uint4 q0, const uint4 q1,
                                        s16x8& hi, s16x8& lo) {
  hi[0] = (short)(q0.x & 0xffffu); lo[0] = (short)(q0.x >> 16);
  hi[1] = (short)(q0.y & 0xffffu); lo[1] = (short)(q0.y >> 16);
  hi[2] = (short)(q0.z & 0xffffu); lo[2] = (short)(q0.z >> 16);
  hi[3] = (short)(q0.w & 0xffffu); lo[3] = (short)(q0.w >> 16);
  hi[4] = (short)(q1.x & 0xffffu); lo[4] = (short)(q1.x >> 16);
  hi[5] = (short)(q1.y & 0xffffu); lo[5] = (short)(q1.y >> 16);
  hi[6] = (short)(q1.z & 0xffffu); lo[6] = (short)(q1.z >> 16);
  hi[7] = (short)(q1.w & 0xffffu); lo[7] = (short)(q1.w >> 16);
}

// Monotonic group barrier: arrive RELAXED, spin RELAXED (sc1 loads, no cache
// maintenance), one ACQUIRE fence (buffer_inv) after the group is complete.
// h-visibility: h stores are sc1 write-through; __syncthreads drains each
// wave's vmcnt before thread0 arrives.
__device__ __forceinline__ void barrier_grp(unsigned* cnt, unsigned target) {
  __syncthreads();
  if (threadIdx.x == 0) {
    __hip_atomic_fetch_add(cnt, 1u, __ATOMIC_RELAXED, __HIP_MEMORY_SCOPE_AGENT);
    int spins = 0;
    while (__hip_atomic_load(cnt, __ATOMIC_RELAXED,
                             __HIP_MEMORY_SCOPE_AGENT) < target) {
      __builtin_amdgcn_s_sleep(1);
      if (++spins > (1 << 20)) break;   // safety: no infinite hang
    }
    __builtin_amdgcn_fence(__ATOMIC_ACQUIRE, "agent");  // one buffer_inv
  }
  __syncthreads();
}

// ---------------------------------------------------------------------------
// Persistent LSTM. wg = [layer(1) | rb(2) | cb(5)]. Per WG: 64 rows (one
// ensemble block) x 64 gate-cols (16 units x 4 gates), weights LDS-resident.
// LDS layout: fragment f (=k/8) of col c lives at 16B slot [f*64 + (c^(f&7))].
// ---------------------------------------------------------------------------
__global__ __launch_bounds__(256, 1) void lstm_persist(
    const float* __restrict__ seq,
    unsigned* __restrict__ h0P, unsigned* __restrict__ h1P,
    const short* __restrict__ Wf, const float* __restrict__ biasF,
    const int* __restrict__ slen, unsigned* __restrict__ bar)
{
  extern __shared__ __align__(16) short Bs[];     // 64 cols x 1024 k = 128 KiB
  const int wg = blockIdx.x;
  const int layer = wg >> 7;
  const int idx = wg & 127;
  const int cb = idx & 31, rb = idx >> 5;         // ensemble e == rb
  const int tid = threadIdx.x, wave = tid >> 6, lane = tid & 63;
  char* bsw = reinterpret_cast<char*>(Bs);

  // ---- stage weight slice into LDS, fragment-linear (coalesced reads) ----
  const short* Wfe = Wf + ((size_t)(layer * 4 + rb) * 2048 + cb * 64) * 1024;
  #pragma unroll
  for (int i = 0; i < 32; ++i) {
    int f = (i << 8) + tid;
    int col = f >> 7, fr = f & 127;               // frag fr holds k = fr*8..+8
    s16x8 v = *reinterpret_cast<const s16x8*>(Wfe + (size_t)col * 1024 + (fr << 3));
    int byo = (fr << 10) + ((col << 4) ^ ((fr & 7) << 4));
    *reinterpret_cast<s16x8*>(bsw + byo) = v;
  }
  __syncthreads();

  const int j = lane & 15;
  const int g = lane >> 4;                        // k-subgroup 0..3
  const int koff = g << 3;
  const int rbase = rb * 64 + wave * 16 + (g << 2);
  const int rowg  = rb * 64 + wave * 16 + j;
  const int u     = cb * 16 + j;
  const float* bp = biasF + (size_t)(layer * 4 + rb) * 2048 + cb * 64 + j;
  const float bi = bp[0], bff = bp[16], bg = bp[32], bo = bp[48];
  int msl[4];
  #pragma unroll
  for (int r = 0; r < 4; ++r) msl[r] = slen[rbase + r];

  float creg[4] = {0.f, 0.f, 0.f, 0.f};
  float hreg[4] = {0.f, 0.f, 0.f, 0.f};
  const size_t BH = (size_t)256 * 512;            // uints per h buffer
  unsigned* cnt = bar + (rb << 5);                // 128B-separated per rb
  const char* bs = bsw;

  for (int t = 0; t <= 256; ++t) {
    const int s = t - layer;
    if (s >= 0 && s < 256) {
      const int cur = s & 1;
      const unsigned* hPrev = (layer ? h1P : h0P) + (size_t)cur * BH;
      unsigned* hOut = (layer ? h1P : h0P) + (size_t)(cur ^ 1) * BH;

      f32x4 acc[4] = {}, accL[4] = {};

      #define MMQ(FRAG, AHI, ALO)                                             \
        {                                                                     \
          const int fb_ = (FRAG) << 10;                                       \
          const int xm_ = ((FRAG) & 7) << 4;                                  \
          _Pragma("unroll")                                                   \
          for (int cf = 0; cf < 4; ++cf) {                                    \
            const int byo_ = fb_ + (((cf << 8) | (j << 4)) ^ xm_);            \
            s16x8 b_ = *reinterpret_cast<const s16x8*>(bs + byo_);            \
            acc[cf] = __builtin_amdgcn_mfma_f32_16x16x32_bf16(                \
                __builtin_bit_cast(bf16x8, AHI),                              \
                __builtin_bit_cast(bf16x8, b_), acc[cf], 0, 0, 0);            \
            accL[cf] = __builtin_amdgcn_mfma_f32_16x16x32_bf16(               \
                __builtin_bit_cast(bf16x8, ALO),                              \
                __builtin_bit_cast(bf16x8, b_), accL[cf], 0, 0, 0);           \
          }                                                                   \
        }

      // half 0 (k 0..511): layer0 <- x fp32 (split on the fly);
      //                    layer1 <- h0 of this step (packed hi|lo).
      if (layer == 0) {
        const float* xr = seq + (size_t)rowg * 131072 + (size_t)s * 512 + koff;
        #pragma unroll 4
        for (int ks = 0; ks < 16; ++ks) {
          const float* p = xr + (ks << 5);
          float4 x0 = *reinterpret_cast<const float4*>(p);
          float4 x1 = *reinterpret_cast<const float4*>(p + 4);
          float xv[8] = {x0.x, x0.y, x0.z, x0.w, x1.x, x1.y, x1.z, x1.w};
          s16x8 ahi, alo;
          #pragma unroll
          for (int q = 0; q < 8; ++q) {
            union { float f; unsigned u; } vv; vv.f = xv[q];
            short h = (short)(vv.u >> 16);        // truncate -> hi
            ahi[q] = h;
            alo[q] = f2bfs(xv[q] - bf2f(h));      // residual -> lo
          }
          MMQ(((ks << 2) | g), ahi, alo)
        }
      } else {
        const unsigned* xp = h0P + (size_t)(cur ^ 1) * BH
                           + (size_t)rowg * 512 + koff;
        #pragma unroll 4
        for (int ks = 0; ks < 16; ++ks) {
          uint4 q0 = *reinterpret_cast<const uint4*>(xp + (ks << 5));
          uint4 q1 = *reinterpret_cast<const uint4*>(xp + (ks << 5) + 4);
          s16x8 ahi, alo; unpack8(q0, q1, ahi, alo);
          MMQ(((ks << 2) | g), ahi, alo)
        }
      }
      // half 1 (k 512..1023): own layer's previous h (packed hi|lo)
      {
        const unsigned* hp = hPrev + (size_t)rowg * 512 + koff;
        #pragma unroll 4
        for (int ks = 0; ks < 16; ++ks) {
          uint4 q0 = *reinterpret_cast<const uint4*>(hp + (ks << 5));
          uint4 q1 = *reinterpret_cast<const uint4*>(hp + (ks << 5) + 4);
          s16x8 ahi, alo; unpack8(q0, q1, ahi, alo);
          MMQ((((16 + ks) << 2) | g), ahi, alo)
        }
      }
      #undef MMQ

      // ---- LSTM cell, state in registers; packed sc1 store ----
      #pragma unroll
      for (int r = 0; r < 4; ++r) {
        const int row = rbase + r;
        float zi = acc[0][r] + accL[0][r] + bi;
        float zf = acc[1][r] + accL[1][r] + bff;
        float zg = acc[2][r] + accL[2][r] + bg;
        float zo = acc[3][r] + accL[3][r] + bo;
        float cn = sigf(zf) * creg[r] + sigf(zi) * tanhf(zg);
        float hn = sigf(zo) * tanhf(cn);
        if (s >= msl[r]) { cn = creg[r]; hn = hreg[r]; }   // masked: carry
        creg[r] = cn; hreg[r] = hn;
        short hh, hl; split2(hn, hh, hl);
        unsigned pk = ((unsigned)(unsigned short)hl << 16)
                    | (unsigned)(unsigned short)hh;
        __hip_atomic_store(&hOut[(size_t)row * 512 + u], pk,
                           __ATOMIC_RELAXED, __HIP_MEMORY_SCOPE_AGENT);
      }
    }
    if (t < 256) barrier_grp(cnt, 64u * (unsigned)(t + 1));
  }
}

// ---------------------------------------------------------------------------
// Head GEMM: 64x64 tile, B (bf16 hi) from global, packed A, 2-term MFMA.
// EPI 1 = relu6 -> packed hi|lo; EPI 2 = f32 out.
// ---------------------------------------------------------------------------
template<int EPI>
__global__ __launch_bounds__(256) void head_gemm(
    const unsigned* __restrict__ a0, int sA0,
    const unsigned* __restrict__ a1, int sA1, int kSplit,
    const short* __restrict__ Wh, const float* __restrict__ bias,
    int N, int K,
    unsigned* __restrict__ outP, float* __restrict__ outf)
{
  const int cb = blockIdx.x, rb = blockIdx.y;     // e == rb
  const int tid = threadIdx.x, wave = tid >> 6, lane = tid & 63;
  const int j = lane & 15;
  const int rowg = rb * 64 + wave * 16 + j;
  const int koff = (lane >> 4) << 3;
  const short* We = Wh + ((size_t)rb * N + cb * 64) * K;
  f32x4 acc[4] = {}, accL[4] = {};
  for (int ks = 0; ks < (K >> 5); ++ks) {
    const int kl = (ks << 5) + koff;
    const unsigned* ap = (kl < kSplit)
        ? (a0 + (size_t)rowg * sA0 + kl)
        : (a1 + (size_t)rowg * sA1 + (kl - kSplit));
    uint4 q0 = *reinterpret_cast<const uint4*>(ap);
    uint4 q1 = *reinterpret_cast<const uint4*>(ap + 4);
    s16x8 ahi, alo; unpack8(q0, q1, ahi, alo);
    #pragma unroll
    for (int cf = 0; cf < 4; ++cf) {
      const int ccol = (cf << 4) + j;
      s16x8 b = *reinterpret_cast<const s16x8*>(We + (size_t)ccol * K + kl);
      acc[cf] = __builtin_amdgcn_mfma_f32_16x16x32_bf16(
          __builtin_bit_cast(bf16x8, ahi), __builtin_bit_cast(bf16x8, b),
          acc[cf], 0, 0, 0);
      accL[cf] = __builtin_amdgcn_mfma_f32_16x16x32_bf16(
          __builtin_bit_cast(bf16x8, alo), __builtin_bit_cast(bf16x8, b),
          accL[cf], 0, 0, 0);
    }
  }
  const int rbase = rb * 64 + wave * 16 + ((lane >> 4) << 2);
  #pragma unroll
  for (int cf = 0; cf < 4; ++cf) {
    const int col = cb * 64 + cf * 16 + j;
    const float bb = bias[(size_t)rb * N + col];
    #pragma unroll
    for (int r = 0; r < 4; ++r) {
      float z = acc[cf][r] + accL[cf][r] + bb;
      if (EPI == 1) {
        z = fminf(fmaxf(z, 0.f), 6.f);
        short hh, hl; split2(z, hh, hl);
        outP[(size_t)(rbase + r) * N + col] =
            ((unsigned)(unsigned short)hl << 16) | (unsigned)(unsigned short)hh;
      } else {
        outf[(size_t)(rbase + r) * N + col] = z;
      }
    }
  }
}

// ---------------------------------------------------------------------------
// Prep: fold alpha/gamma into per-ensemble bf16 (hi-only) weights.
// LSTM layout: Wf[le][c'][k], c' = ublk*64 + gate*16 + unit_lo, k = W|U.
// ---------------------------------------------------------------------------
__global__ __launch_bounds__(256) void fold_lstm(
    const float* __restrict__ W, const float* __restrict__ U,
    const float* __restrict__ al, const float* __restrict__ ral,
    const float* __restrict__ ga, const float* __restrict__ rga,
    short* __restrict__ Wf)
{
  __shared__ float T[64][65];
  const int tid = threadIdx.x;
  const int kb = blockIdx.x * 64;   // over K=1024 (W 512 | U 512)
  const int cb = blockIdx.y;        // ublk 0..31
  const int le = blockIdx.z;        // l*4+e
  const int l  = le >> 2;
  const int kl = tid >> 2;
  const int g  = tid & 3;
  const int k  = kb + kl;
  const bool isW = k < 512;
  const int kk = isW ? k : k - 512;
  const float* src = (isW ? W : U) + ((size_t)l * 512 + kk) * 2048;
  const float  a   = (isW ? al : ral)[(size_t)le * 512 + kk];
  const float* gam = (isW ? ga : rga) + (size_t)le * 2048;
  const int colBase = g * 512 + cb * 16;
  const float4* s4 = reinterpret_cast<const float4*>(src + colBase);
  const float4* g4 = reinterpret_cast<const float4*>(gam + colBase);
  #pragma unroll
  for (int q = 0; q < 4; ++q) {
    float4 v = s4[q], gv = g4[q];
    T[kl][g * 16 + q * 4 + 0] = v.x * a * gv.x;
    T[kl][g * 16 + q * 4 + 1] = v.y * a * gv.y;
    T[kl][g * 16 + q * 4 + 2] = v.z * a * gv.z;
    T[kl][g * 16 + q * 4 + 3] = v.w * a * gv.w;
  }
  __syncthreads();
  const int cl = tid >> 2, kq0 = (tid & 3) * 16;
  alignas(16) short tH[16];
  #pragma unroll
  for (int q = 0; q < 16; ++q) tH[q] = f2bfs(T[kq0 + q][cl]);
  size_t dst = ((size_t)le * 2048 + cb * 64 + cl) * 1024 + kb + kq0;
  *reinterpret_cast<s16x8*>(Wf + dst)     = *reinterpret_cast<s16x8*>(tH);
  *reinterpret_cast<s16x8*>(Wf + dst + 8) = *reinterpret_cast<s16x8*>(tH + 8);
}

// Head: dst[e][col][k] = src[k][col]*alpha[e][k]*gamma[e][col]  (hi only)
__global__ __launch_bounds__(256) void fold_plain(
    const float* __restrict__ src, const float* __restrict__ al,
    const float* __restrict__ ga, short* __restrict__ dst, int N, int K)
{
  __shared__ float T[64][65];
  const int tid = threadIdx.x;
  const int kb = blockIdx.x * 64;
  const int nb = blockIdx.y;
  const int e  = blockIdx.z;
  const int kl = tid >> 2;
  const int c0 = (tid & 3) * 16;
  const int k  = kb + kl;
  const float a = al[(size_t)e * K + k];
  const int colBase = nb * 64 + c0;
  const float4* s4 = reinterpret_cast<const float4*>(src + (size_t)k * N + colBase);
  const float4* g4 = reinterpret_cast<const float4*>(ga + (size_t)e * N + colBase);
  #pragma unroll
  for (int q = 0; q < 4; ++q) {
    float4 v = s4[q], gv = g4[q];
    T[kl][c0 + q * 4 + 0] = v.x * a * gv.x;
    T[kl][c0 + q * 4 + 1] = v.y * a * gv.y;
    T[kl][c0 + q * 4 + 2] = v.z * a * gv.z;
    T[kl][c0 + q * 4 + 3] = v.w * a * gv.w;
  }
  __syncthreads();
  const int cl = tid >> 2, kq0 = (tid & 3) * 16;
  alignas(16) short tH[16];
  #pragma unroll
  for (int q = 0; q < 16; ++q) tH[q] = f2bfs(T[kq0 + q][cl]);
  size_t d = ((size_t)e * N + nb * 64 + cl) * K + kb + kq0;
  *reinterpret_cast<s16x8*>(dst + d)     = *reinterpret_cast<s16x8*>(tH);
  *reinterpret_cast<s16x8*>(dst + d + 8) = *reinterpret_cast<s16x8*>(tH + 8);
}

__global__ void fold_bias_lstm(const float* __restrict__ b, float* __restrict__ bf) {
  int idx = blockIdx.x * 256 + threadIdx.x;          // 16384
  int cp = idx & 2047, le = idx >> 11;
  int ublk = cp >> 6, g = (cp >> 4) & 3, jj = cp & 15;
  bf[idx] = b[(size_t)le * 2048 + g * 512 + ublk * 16 + jj];
}

__global__ void cvt_pack(const float* __restrict__ s,
                         unsigned* __restrict__ d, int n) {
  int i = blockIdx.x * blockDim.x + threadIdx.x;
  if (i < n) {
    short h, l; split2(s[i], h, l);
    d[i] = ((unsigned)(unsigned short)l << 16) | (unsigned)(unsigned short)h;
  }
}

__global__ void zero_ws(float4* p, int n) {
  int i = blockIdx.x * blockDim.x + threadIdx.x;
  if (i < n) p[i] = make_float4(0.f, 0.f, 0.f, 0.f);
}

__global__ void init_bar(unsigned* bar) {
  if (threadIdx.x < 128) bar[threadIdx.x] = 0u;
}

// ---------------------------------------------------------------------------
// workspace layout (bytes)
// ---------------------------------------------------------------------------
constexpr size_t OFF_WF    = 0;                      // 2*4*2048*1024*2 = 33554432
constexpr size_t OFF_WHID  = 33554432;               // 4*256*768*2     = 1572864
constexpr size_t OFF_WOUT  = OFF_WHID + 1572864;     // 4*64*256*2      = 131072
constexpr size_t OFF_BIASF = OFF_WOUT + 131072;      // 16384*4         = 65536
constexpr size_t OFF_CTXP  = OFF_BIASF + 65536;      // 65536*4         = 262144
constexpr size_t OFF_H0P   = OFF_CTXP + 262144;      // 2*256*512*4     = 1048576
constexpr size_t OFF_H1P   = OFF_H0P + 1048576;      // 1048576
constexpr size_t OFF_HIDP  = OFF_H1P + 1048576;      // 256*256*4       = 262144
constexpr size_t OFF_BAR   = OFF_HIDP + 262144;      // 512

extern "C" void kernel_launch(void* const* d_in, const int* in_sizes, int n_in,
                              void* d_out, int out_size, void* d_ws, size_t ws_size,
                              hipStream_t stream) {
  (void)in_sizes; (void)n_in; (void)out_size; (void)ws_size;
  const float* seq  = (const float*)d_in[0];
  const float* ctx  = (const float*)d_in[1];
  const int*   slen = (const int*)d_in[2];
  const float* lW   = (const float*)d_in[3];
  const float* lU   = (const float*)d_in[4];
  const float* lb   = (const float*)d_in[5];
  const float* lal  = (const float*)d_in[6];
  const float* lga  = (const float*)d_in[7];
  const float* lral = (const float*)d_in[8];
  const float* lrga = (const float*)d_in[9];
  const float* hW   = (const float*)d_in[10];
  const float* hb   = (const float*)d_in[11];
  const float* hal  = (const float*)d_in[12];
  const float* hga  = (const float*)d_in[13];
  const float* oW   = (const float*)d_in[14];
  const float* ob   = (const float*)d_in[15];
  const float* oal  = (const float*)d_in[16];
  const float* oga  = (const float*)d_in[17];

  char* ws = (char*)d_ws;
  short*    Wf    = (short*)(ws + OFF_WF);
  short*    Whid  = (short*)(ws + OFF_WHID);
  short*    Wout  = (short*)(ws + OFF_WOUT);
  float*    biasF = (float*)(ws + OFF_BIASF);
  unsigned* ctxP  = (unsigned*)(ws + OFF_CTXP);
  unsigned* h0P   = (unsigned*)(ws + OFF_H0P);
  unsigned* h1P   = (unsigned*)(ws + OFF_H1P);
  unsigned* hidP  = (unsigned*)(ws + OFF_HIDP);
  unsigned* bar   = (unsigned*)(ws + OFF_BAR);

  // allow 128 KiB dynamic LDS
  (void)hipFuncSetAttribute(reinterpret_cast<const void*>(lstm_persist),
                            hipFuncAttributeMaxDynamicSharedMemorySize, 131072);

  // prep (every call: deterministic, no caching)
  fold_lstm<<<dim3(16, 32, 8), 256, 0, stream>>>(lW, lU, lal, lral, lga, lrga, Wf);
  fold_plain<<<dim3(12, 4, 4), 256, 0, stream>>>(hW, hal, hga, Whid, 256, 768);
  fold_plain<<<dim3(4, 1, 4), 256, 0, stream>>>(oW, oal, oga, Wout, 64, 256);
  fold_bias_lstm<<<64, 256, 0, stream>>>(lb, biasF);
  cvt_pack<<<256, 256, 0, stream>>>(ctx, ctxP, 65536);
  zero_ws<<<512, 256, 0, stream>>>((float4*)(ws + OFF_H0P), 2097152 / 16);
  init_bar<<<1, 128, 0, stream>>>(bar);

  // the whole recurrence in one persistent kernel
  lstm_persist<<<256, 256, 131072, stream>>>(seq, h0P, h1P, Wf, biasF, slen, bar);

  // head: hidden = relu6(((h1,ctx)*a)@hid_W*g + b); out = ((hid*a)@out_W*g + b)
  head_gemm<1><<<dim3(4, 4), 256, 0, stream>>>(
      h1P /* final h1 in buf0 */, 512,
      ctxP, 256, 512,
      Whid, hb, 256, 768, hidP, nullptr);
  head_gemm<2><<<dim3(1, 4), 256, 0, stream>>>(
      hidP, 256,
      hidP, 256, 256,
      Wout, ob, 64, 256,
      nullptr, (float*)d_out);
}